// Round 21
// baseline (347.171 us; speedup 1.0000x reference)
//
#include <hip/hip_runtime.h>
#include <hip/hip_bf16.h>
#include <stdint.h>

typedef __bf16 bf16;
typedef __bf16 bf16x4 __attribute__((ext_vector_type(4)));
typedef __bf16 bf16x8 __attribute__((ext_vector_type(8)));
typedef float f32x4 __attribute__((ext_vector_type(4)));

#define MFMA_BF16(a, b, c) __builtin_amdgcn_mfma_f32_16x16x32_bf16((a), (b), (c), 0, 0, 0)

// log2(e), and the Q pre-scale folding 1/sqrt(hd) into log2 domain
#define LOG2E 1.4426950408889634f
#define QSCALE (0.17677669529663687f * 1.4426950408889634f)

// async global->LDS, 16B per lane, dest = uniform base + lane*16
#define GLL16(gp, lp)                                                          \
  __builtin_amdgcn_global_load_lds(                                            \
      (const __attribute__((address_space(1))) unsigned int*)(gp),             \
      (__attribute__((address_space(3))) unsigned int*)(lp), 16, 0, 0)

// ---------------------------------------------------------------------------
// helpers
// ---------------------------------------------------------------------------
__device__ __forceinline__ void load16f(const float* p, float* r) {
#pragma unroll
  for (int i = 0; i < 4; ++i) {
    float4 v = *(const float4*)(p + 4 * i);
    r[4 * i + 0] = v.x; r[4 * i + 1] = v.y; r[4 * i + 2] = v.z; r[4 * i + 3] = v.w;
  }
}

__device__ __forceinline__ void store16_bf16(bf16* dst, const float* r) {
  bf16x8 v0, v1;
#pragma unroll
  for (int i = 0; i < 8; ++i) { v0[i] = (bf16)r[i]; v1[i] = (bf16)r[8 + i]; }
  *(bf16x8*)(dst) = v0;
  *(bf16x8*)(dst + 8) = v1;
}

// ---------------------------------------------------------------------------
// Kernel A: fp32 -> bf16 conversion, W ONLY now (196K elems, ~1.5 us).
// X is converted in-loop by qkv_gemm's reg-staged A path (proj-proven).
// ---------------------------------------------------------------------------
__global__ __launch_bounds__(256)
void cvt_bf16(const float* __restrict__ Wq, bf16* __restrict__ Wqb)
{
  const unsigned t = blockIdx.x * 256 + threadIdx.x;    // 24576 threads
  const float4 a = ((const float4*)(Wq + (size_t)t * 8))[0];
  const float4 b = ((const float4*)(Wq + (size_t)t * 8))[1];
  bf16x8 v;
  v[0] = (bf16)a.x; v[1] = (bf16)a.y; v[2] = (bf16)a.z; v[3] = (bf16)a.w;
  v[4] = (bf16)b.x; v[5] = (bf16)b.y; v[6] = (bf16)b.z; v[7] = (bf16)b.w;
  *(bf16x8*)(Wqb + (size_t)t * 8) = v;
}

// ---------------------------------------------------------------------------
// Kernel 0: per-fragment rel-pos bias, PRE-MULTIPLIED by log2(e), stored
// BF16 with each fused-loop iteration's 8 values contiguous:
//   biasB[h][qt][ks(8)][g][li] [p(2)][r(4)]  (16B per (thread,ks))
//   key = 32*ks + 8*g + 4*p + r   (p = tile parity, tiles 2ks, 2ks+1)
// ---------------------------------------------------------------------------
__global__ void bias_pre(const float* __restrict__ rel, bf16* __restrict__ biasB)
{
  const int t = blockIdx.x * 256 + threadIdx.x;          // 16384 threads
  const int li = t & 15, g = (t >> 4) & 3, ks = (t >> 6) & 7;
  const int qt = (t >> 9) & 3, h = (t >> 11) & 7;
  const int n = qt * 16 + li, ni = n >> 3, nj = n & 7;
  bf16x8 v;
#pragma unroll
  for (int u = 0; u < 8; ++u) {
    const int p = u >> 2, r = u & 3;
    const int key = 32 * ks + 8 * g + 4 * p + r;
    const int ki = key >> 4, kj = key & 15;
    const int bi = (ni + 19 - ki) * 31 + (nj + 19 - kj);
    v[u] = (bf16)(rel[bi * 8 + h] * LOG2E);
  }
  ((bf16x8*)biasB)[t] = v;
}

// ---------------------------------------------------------------------------
// Kernel 1: qkv = x @ wb.T + qkv_b  (hybrid staging, proj-proven recipe):
//   A (= X, fp32) reg-staged: load16f kt+2 ahead -> store16_bf16 into a
//     PADDED dbuf (LD=40)  [removes the separate 201MB cvt pass]
//   B (= Wqb, bf16) via global_load_lds into linear dbuf.
// One barrier per K-step. XCD-contiguous work id.
// V written d-INTERLEAVED 4-token-blocked:
//   Vg[h][tok>>2][(d&15)*2 + (d>>4)][tok&3]
// ---------------------------------------------------------------------------
__global__ __launch_bounds__(256, 2)
void qkv_gemm(const float* __restrict__ X, const bf16* __restrict__ W,
              const float* __restrict__ bias,
              bf16* __restrict__ Qb, bf16* __restrict__ Kb, bf16* __restrict__ Vg)
{
  __shared__ bf16 As[2][128 * 40];   // padded, reg-staged fp32->bf16
  __shared__ bf16 Bs[2][128 * 32];   // linear, gload_lds dest

  const int tid = threadIdx.x;
  const int lane = tid & 63, wave = tid >> 6;
  const int bid = blockIdx.x;
  const int wid = (bid & 7) * 768 + (bid >> 3);   // XCD-contiguous work id
  const int bn = wid % 6, bm = wid / 6;
  const int m0 = bm * 128, n0 = bn * 128;
  const int sr = tid >> 1, sc = (tid & 1) * 16;
  const int wr = (wave >> 1) * 64, wc = (wave & 1) * 64;
  const int g = lane >> 4, li = lane & 15;

  const float* Ap = X + (size_t)(m0 + sr) * 256 + sc;
  const bf16* bgp = W + (size_t)(n0 + (tid >> 2)) * 256 + (tid & 3) * 8;
  const int lofs = wave * 512;                     // elems; byte = wave*1024

  const f32x4 fzero = {0.f, 0.f, 0.f, 0.f};
  f32x4 acc[4][4];
#pragma unroll
  for (int i = 0; i < 4; ++i)
#pragma unroll
    for (int j = 0; j < 4; ++j) acc[i][j] = fzero;

  float aR[16];
  load16f(Ap, aR);
  GLL16(bgp,            &Bs[0][lofs]);
  GLL16(bgp + 64 * 256, &Bs[0][lofs + 2048]);
  store16_bf16(&As[0][sr * 40 + sc], aR);
  load16f(Ap + 32, aR);
  __syncthreads();

#pragma unroll 1
  for (int kt = 0; kt < 8; ++kt) {
    const int cur = kt & 1;
    if (kt < 7) {
      GLL16(bgp + (kt + 1) * 32,            &Bs[cur ^ 1][lofs]);
      GLL16(bgp + (kt + 1) * 32 + 64 * 256, &Bs[cur ^ 1][lofs + 2048]);
      store16_bf16(&As[cur ^ 1][sr * 40 + sc], aR);
      if (kt < 6) load16f(Ap + (kt + 2) * 32, aR);
    }
    bf16x8 af[4], bfr[4];
#pragma unroll
    for (int t = 0; t < 4; ++t) {
      af[t]  = *(const bf16x8*)&As[cur][(wr + t * 16 + li) * 40 + g * 8];
      bfr[t] = *(const bf16x8*)&Bs[cur][(wc + t * 16 + li) * 32 + g * 8];
    }
#pragma unroll
    for (int i = 0; i < 4; ++i)
#pragma unroll
      for (int j = 0; j < 4; ++j)
        acc[i][j] = MFMA_BF16(af[i], bfr[j], acc[i][j]);
    __syncthreads();
  }

  // epilogue: row = m0+wr+i*16+g*4+r (4-aligned), col = n0+wc+j*16+li
#pragma unroll
  for (int i = 0; i < 4; ++i) {
    const int row = m0 + wr + i * 16 + g * 4;
#pragma unroll
    for (int j = 0; j < 4; ++j) {
      const int col = n0 + wc + j * 16 + li;
      const float bv = bias[col];
      const int which = col >> 8;                 // 0=q 1=k 2=v
      if (which == 2) {
        const int hh = (col >> 5) & 7, d = col & 31;
        bf16x4 pv;
#pragma unroll
        for (int r = 0; r < 4; ++r) pv[r] = (bf16)(acc[i][j][r] + bv);
        // d-interleaved: row index (d&15)*2 + (d>>4) within the 128-elem blk
        const int drow = ((d & 15) << 1) | (d >> 4);
        *(bf16x4*)(Vg + (((size_t)hh) << 22) + (size_t)(row >> 2) * 128 + drow * 4) = pv;
      } else {
        bf16* dst = which == 0 ? Qb : Kb;
        const float sc2 = which == 0 ? QSCALE : 1.0f;   // fold scale*log2e into Q
        const size_t base = (size_t)((col >> 5) & 7) * (131072u * 32u) + (size_t)(col & 31);
#pragma unroll
        for (int r = 0; r < 4; ++r)
          dst[base + (size_t)(row + r) * 32u] = (bf16)((acc[i][j][r] + bv) * sc2);
      }
    }
  }
}

// ---------------------------------------------------------------------------
// Kernel 2: window attention. Block = (window, head), 4 waves.
// (byte-identical to round 20 best: fused QK->exp->PV, raw v_exp_f32,
// distance-1 V prefetch, bf16x8 bias, d-interleaved 16B V loads)
// ---------------------------------------------------------------------------
__global__ __launch_bounds__(256)
void win_attn(const bf16* __restrict__ Qb, const bf16* __restrict__ Kb,
              const bf16* __restrict__ Vg, const bf16* __restrict__ biasB,
              bf16* __restrict__ Ob)
{
  constexpr int LDK = 40;
  __shared__ bf16 Ks[256 * LDK];     // sigma-row order, 20480 B

  const int tid = threadIdx.x;
  const int lane = tid & 63, qt = tid >> 6;
  const int li = lane & 15, g = lane >> 4;
  const int bid = blockIdx.x;
  const int h = bid & 7, w = bid >> 3;       // head fastest -> head-per-XCD
  const int b = w >> 8, wi = (w >> 4) & 15, wj = w & 15;
  const int btok = b << 14;

  // ---- Q fragment (B-operand), coalesced global ----
  const int q = qt * 16 + li;
  const int tokq = btok + (wi * 8 + (q >> 3)) * 128 + (wj * 8 + (q & 7));
  const bf16x8 qf = *(const bf16x8*)(Qb + ((((size_t)h) << 17) + tokq) * 32 + g * 8);

  // ---- stage K: 4 lanes per halo token, sigma-permuted LDS row write ----
  {
    const size_t hb = ((size_t)h) << 17;
#pragma unroll
    for (int it = 0; it < 4; ++it) {
      const int u = it * 256 + tid;
      const int m = u >> 2, c = u & 3;
      const int hi = m >> 4, hj = m & 15;
      const int gi = wi * 8 - 4 + hi, gj = wj * 8 - 4 + hj;
      const bool ok = ((unsigned)gi < 128u) && ((unsigned)gj < 128u);
      uint4 kv{};
      if (ok) kv = *(const uint4*)(Kb + (hb + (size_t)(btok + gi * 128 + gj)) * 32 + c * 8);
      const int si = ((hi & 1) << 3) | ((hj >> 3) << 2) | (hj & 3);
      const int kt = ((hi >> 1) << 1) | ((hj >> 2) & 1);
      *(uint4*)&Ks[(kt * 16 + si) * LDK + c * 8] = kv;
    }
  }
  __syncthreads();

  // ---- fused QK -> exp -> PV over 8 sigma-tile pairs ----
  const bf16* bB = biasB + (size_t)(h * 4 + qt) * 4096 + (g * 16 + li) * 8;
  const f32x4 z4 = {0.f, 0.f, 0.f, 0.f};
  f32x4 o0 = z4, o1 = z4, o2 = z4;
  const bf16 one1 = (bf16)1.0f;
  const bf16x8 vones = {one1, one1, one1, one1, one1, one1, one1, one1};

  const int g1 = g & 1, g2 = g >> 1;
  const int gj0 = wj * 8 - 4 + 8 * g1;                  // 4-aligned col start
  const bool c0ok = (unsigned)gj0 < 128u;
  const bool c1ok = (unsigned)(gj0 + 4) < 128u;
  const int gi0 = wi * 8 - 4 + g2;
  // base: Vg[h][btok>>2 ...][li*8] (d-interleaved layout)
  const bf16* vb = Vg + (((size_t)h) << 22) + (size_t)(btok >> 2) * 128 + li * 8;
  const int q4a = gj0 >> 2;                             // may be negative; guarded

  // preload packed V fragments for ks = 0 (L = tokens 0-3, M = tokens 4-7;
  // each holds [d=li (4 tok), d=li+16 (4 tok)])
  bf16x8 L{}, M{};
  {
    const bool rok = (unsigned)gi0 < 128u;
    if (rok & c0ok) L = *(const bf16x8*)(vb + (size_t)(gi0 * 32 + q4a) * 128);
    if (rok & c1ok) M = *(const bf16x8*)(vb + (size_t)(gi0 * 32 + q4a + 1) * 128);
  }

#pragma unroll
  for (int ks = 0; ks < 8; ++ks) {
    // bias for tiles 2ks, 2ks+1 (bf16 -> f32 C-init)
    const bf16x8 bb = *(const bf16x8*)(bB + ks * 512);
    f32x4 cA, cB;
#pragma unroll
    for (int r = 0; r < 4; ++r) { cA[r] = (float)bb[r]; cB[r] = (float)bb[4 + r]; }

    // QK^T for sigma tiles 2ks, 2ks+1 (bias via accumulator init)
    const bf16x8 kf0 = *(const bf16x8*)&Ks[((2 * ks) * 16 + li) * LDK + g * 8];
    const bf16x8 kf1 = *(const bf16x8*)&Ks[((2 * ks + 1) * 16 + li) * LDK + g * 8];
    const f32x4 s0 = MFMA_BF16(kf0, qf, cA);
    const f32x4 s1 = MFMA_BF16(kf1, qf, cB);

    // distance-1 prefetch: packed V for iteration ks+1
    bf16x8 nL{}, nM{};
    if (ks < 7) {
      const int gi = gi0 + 2 * (ks + 1);
      const bool rok = (unsigned)gi < 128u;
      if (rok & c0ok) nL = *(const bf16x8*)(vb + (size_t)(gi * 32 + q4a) * 128);
      if (rok & c1ok) nM = *(const bf16x8*)(vb + (size_t)(gi * 32 + q4a + 1) * 128);
    }

    // raw exp2 -> bf16 P fragment (in-lane via sigma order)
    bf16x8 pb;
#pragma unroll
    for (int u = 0; u < 4; ++u) {
      pb[u]     = (bf16)__builtin_amdgcn_exp2f(s0[u]);
      pb[u + 4] = (bf16)__builtin_amdgcn_exp2f(s1[u]);
    }
    // unpack: vf0 = [L.d=li, M.d=li], vf1 = [L.d=li+16, M.d=li+16]
    const bf16x8 vf0 = __builtin_shufflevector(L, M, 0, 1, 2, 3, 8, 9, 10, 11);
    const bf16x8 vf1 = __builtin_shufflevector(L, M, 4, 5, 6, 7, 12, 13, 14, 15);
    o0 = MFMA_BF16(vf0, pb, o0);
    o1 = MFMA_BF16(vf1, pb, o1);
    o2 = MFMA_BF16(vones, pb, o2);

    L = nL; M = nM;
  }
  const float inv = __builtin_amdgcn_rcpf(o2[0]);

  // ---- epilogue: O[tokq][h*32 + dt*16 + 4g + r] = O^T/sum ----
  bf16* op = Ob + (size_t)tokq * 256 + h * 32 + 4 * g;
  bf16x4 w0, w1;
#pragma unroll
  for (int r = 0; r < 4; ++r) {
    w0[r] = (bf16)(o0[r] * inv);
    w1[r] = (bf16)(o1[r] * inv);
  }
  *(bf16x4*)(op) = w0;
  *(bf16x4*)(op + 16) = w1;
}

// ---------------------------------------------------------------------------
// Kernel 3: out = attn_out @ proj_w.T + proj_b   (fp32 output to d_out)
// 2-phase: A (bf16) via global_load_lds into linear dbuf LDS; B (fp32 W)
// reg-staged+converted into padded dbuf LDS. One barrier per K-step.
// ---------------------------------------------------------------------------
__global__ __launch_bounds__(256, 2)
void proj_gemm(const bf16* __restrict__ A, const float* __restrict__ W,
               const float* __restrict__ bias, float* __restrict__ Out)
{
  __shared__ bf16 As[2][128 * 32];   // linear, gload_lds dest
  __shared__ bf16 Bs[2][128 * 40];   // padded, reg-staged

  const int tid = threadIdx.x;
  const int lane = tid & 63, wave = tid >> 6;
  const int bid = blockIdx.x;
  const int wid = (bid & 7) * 256 + (bid >> 3);   // XCD-contiguous work id
  const int bn = wid & 1, bm = wid >> 1;
  const int m0 = bm * 128, n0 = bn * 128;
  const int sr = tid >> 1, sc = (tid & 1) * 16;
  const int wr = (wave >> 1) * 64, wc = (wave & 1) * 64;
  const int g = lane >> 4, li = lane & 15;

  const bf16* agp = A + (size_t)(m0 + (tid >> 2)) * 256 + (tid & 3) * 8;
  const float* Bp = W + (size_t)(n0 + sr) * 256 + sc;
  const int lofs = wave * 512;

  const f32x4 fzero = {0.f, 0.f, 0.f, 0.f};
  f32x4 acc[4][4];
#pragma unroll
  for (int i = 0; i < 4; ++i)
#pragma unroll
    for (int j = 0; j < 4; ++j) acc[i][j] = fzero;

  float bR[16];
  load16f(Bp, bR);
  GLL16(agp,            &As[0][lofs]);
  GLL16(agp + 64 * 256, &As[0][lofs + 2048]);
  store16_bf16(&Bs[0][sr * 40 + sc], bR);
  load16f(Bp + 32, bR);
  __syncthreads();

#pragma unroll 1
  for (int kt = 0; kt < 8; ++kt) {
    const int cur = kt & 1;
    if (kt < 7) {
      GLL16(agp + (kt + 1) * 32,            &As[cur ^ 1][lofs]);
      GLL16(agp + (kt + 1) * 32 + 64 * 256, &As[cur ^ 1][lofs + 2048]);
      store16_bf16(&Bs[cur ^ 1][sr * 40 + sc], bR);
      if (kt < 6) load16f(Bp + (kt + 2) * 32, bR);
    }
    bf16x8 af[4], bfr[4];
#pragma unroll
    for (int t = 0; t < 4; ++t) {
      af[t]  = *(const bf16x8*)&As[cur][(wr + t * 16 + li) * 32 + g * 8];
      bfr[t] = *(const bf16x8*)&Bs[cur][(wc + t * 16 + li) * 40 + g * 8];
    }
#pragma unroll
    for (int i = 0; i < 4; ++i)
#pragma unroll
      for (int j = 0; j < 4; ++j)
        acc[i][j] = MFMA_BF16(af[i], bfr[j], acc[i][j]);
    __syncthreads();
  }

#pragma unroll
  for (int i = 0; i < 4; ++i) {
    const int row = m0 + wr + i * 16 + g * 4;
#pragma unroll
    for (int j = 0; j < 4; ++j) {
      const int col = n0 + wc + j * 16 + li;
      const float bv = bias[col];
#pragma unroll
      for (int r = 0; r < 4; ++r)
        Out[(size_t)(row + r) * 256 + col] = acc[i][j][r] + bv;
    }
  }
}

// ---------------------------------------------------------------------------
extern "C" void kernel_launch(void* const* d_in, const int* in_sizes, int n_in,
                              void* d_out, int out_size, void* d_ws, size_t ws_size,
                              hipStream_t stream)
{
  const float* x       = (const float*)d_in[0];
  // d_in[1] = mask: unused by the reference
  const float* qkv_w   = (const float*)d_in[2];
  const float* qkv_b   = (const float*)d_in[3];
  const float* proj_w  = (const float*)d_in[4];
  const float* proj_b  = (const float*)d_in[5];
  const float* rel_tab = (const float*)d_in[6];
  float* out = (float*)d_out;

  char* ws = (char*)d_ws;
  bf16* Qb = (bf16*)(ws);                            // [8h][131072][32]       64 MiB
  bf16* Kb = (bf16*)(ws + (size_t)67108864);         // [8h][131072][32]       64 MiB
  bf16* Vg = (bf16*)(ws + (size_t)134217728);        // [8h][32768][64][4]     64 MiB
  bf16* Ao = (bf16*)(ws + (size_t)201326592);        // [131072][256]          64 MiB
  // d_out scratch (proj_gemm overwrites all of d_out at the end):
  bf16*  biasB = (bf16*)d_out;                           // 256 KB
  bf16*  Wqb   = (bf16*)((char*)d_out + 1048576);        // 384 KB

  cvt_bf16<<<dim3(96), dim3(256), 0, stream>>>(qkv_w, Wqb);
  bias_pre<<<dim3(64), dim3(256), 0, stream>>>(rel_tab, biasB);
  qkv_gemm<<<dim3(6144), dim3(256), 0, stream>>>(x, Wqb, qkv_b, Qb, Kb, Vg);
  win_attn<<<dim3(16384), dim3(256), 0, stream>>>(Qb, Kb, Vg, biasB, Ao);
  proj_gemm<<<dim3(2048), dim3(256), 0, stream>>>(Ao, proj_w, proj_b, out);
}

// Round 22
// 305.160 us; speedup vs baseline: 1.1377x; 1.1377x over previous
//
#include <hip/hip_runtime.h>
#include <hip/hip_bf16.h>
#include <stdint.h>

typedef __bf16 bf16;
typedef __bf16 bf16x4 __attribute__((ext_vector_type(4)));
typedef __bf16 bf16x8 __attribute__((ext_vector_type(8)));
typedef float f32x4 __attribute__((ext_vector_type(4)));

#define MFMA_BF16(a, b, c) __builtin_amdgcn_mfma_f32_16x16x32_bf16((a), (b), (c), 0, 0, 0)

// log2(e), and the Q pre-scale folding 1/sqrt(hd) into log2 domain
#define LOG2E 1.4426950408889634f
#define QSCALE (0.17677669529663687f * 1.4426950408889634f)

// async global->LDS, 16B per lane, dest = uniform base + lane*16
#define GLL16(gp, lp)                                                          \
  __builtin_amdgcn_global_load_lds(                                            \
      (const __attribute__((address_space(1))) unsigned int*)(gp),             \
      (__attribute__((address_space(3))) unsigned int*)(lp), 16, 0, 0)

// ---------------------------------------------------------------------------
// helpers
// ---------------------------------------------------------------------------
__device__ __forceinline__ void load16f(const float* p, float* r) {
#pragma unroll
  for (int i = 0; i < 4; ++i) {
    float4 v = *(const float4*)(p + 4 * i);
    r[4 * i + 0] = v.x; r[4 * i + 1] = v.y; r[4 * i + 2] = v.z; r[4 * i + 3] = v.w;
  }
}

__device__ __forceinline__ void store16_bf16(bf16* dst, const float* r) {
  bf16x8 v0, v1;
#pragma unroll
  for (int i = 0; i < 8; ++i) { v0[i] = (bf16)r[i]; v1[i] = (bf16)r[8 + i]; }
  *(bf16x8*)(dst) = v0;
  *(bf16x8*)(dst + 8) = v1;
}

// ---------------------------------------------------------------------------
// Kernel A: fp32 -> bf16 conversion for x (33.5M) and qkv_w (196K).
// ---------------------------------------------------------------------------
__global__ __launch_bounds__(256)
void cvt_bf16(const float* __restrict__ X, const float* __restrict__ Wq,
              bf16* __restrict__ Xb, bf16* __restrict__ Wqb)
{
  const unsigned t = blockIdx.x * 256 + threadIdx.x;
  const float* src;
  bf16* dst;
  if (t < 4194304u) { src = X + (size_t)t * 8; dst = Xb + (size_t)t * 8; }
  else {
    const unsigned u = t - 4194304u;     // 24576 threads for W
    src = Wq + (size_t)u * 8; dst = Wqb + (size_t)u * 8;
  }
  const float4 a = ((const float4*)src)[0];
  const float4 b = ((const float4*)src)[1];
  bf16x8 v;
  v[0] = (bf16)a.x; v[1] = (bf16)a.y; v[2] = (bf16)a.z; v[3] = (bf16)a.w;
  v[4] = (bf16)b.x; v[5] = (bf16)b.y; v[6] = (bf16)b.z; v[7] = (bf16)b.w;
  *(bf16x8*)dst = v;
}

// ---------------------------------------------------------------------------
// Kernel 0: per-fragment rel-pos bias, PRE-MULTIPLIED by log2(e), stored
// BF16 with each fused-loop iteration's 8 values contiguous:
//   biasB[h][qt][ks(8)][g][li] [p(2)][r(4)]  (16B per (thread,ks))
//   key = 32*ks + 8*g + 4*p + r   (p = tile parity, tiles 2ks, 2ks+1)
// ---------------------------------------------------------------------------
__global__ void bias_pre(const float* __restrict__ rel, bf16* __restrict__ biasB)
{
  const int t = blockIdx.x * 256 + threadIdx.x;          // 16384 threads
  const int li = t & 15, g = (t >> 4) & 3, ks = (t >> 6) & 7;
  const int qt = (t >> 9) & 3, h = (t >> 11) & 7;
  const int n = qt * 16 + li, ni = n >> 3, nj = n & 7;
  bf16x8 v;
#pragma unroll
  for (int u = 0; u < 8; ++u) {
    const int p = u >> 2, r = u & 3;
    const int key = 32 * ks + 8 * g + 4 * p + r;
    const int ki = key >> 4, kj = key & 15;
    const int bi = (ni + 19 - ki) * 31 + (nj + 19 - kj);
    v[u] = (bf16)(rel[bi * 8 + h] * LOG2E);
  }
  ((bf16x8*)biasB)[t] = v;
}

// ---------------------------------------------------------------------------
// Kernel 1: qkv = xb @ wb.T + qkv_b  (pure bf16 GEMM).
// m97-style 2-phase gload_lds staging, one barrier per K-step.
// V written d-INTERLEAVED 4-token-blocked:
//   Vg[h][tok>>2][(d&15)*2 + (d>>4)][tok&3]
// so win_attn gets both d-halves of a lane in ONE 16B load.
// ---------------------------------------------------------------------------
__global__ __launch_bounds__(256, 2)
void qkv_gemm(const bf16* __restrict__ X, const bf16* __restrict__ W,
              const float* __restrict__ bias,
              bf16* __restrict__ Qb, bf16* __restrict__ Kb, bf16* __restrict__ Vg)
{
  __shared__ bf16 As[2][128 * 32];
  __shared__ bf16 Bs[2][128 * 32];

  const int tid = threadIdx.x;
  const int lane = tid & 63, wave = tid >> 6;
  const int bid = blockIdx.x;
  const int wid = (bid & 7) * 768 + (bid >> 3);   // XCD-contiguous work id
  const int bn = wid % 6, bm = wid / 6;
  const int m0 = bm * 128, n0 = bn * 128;
  const int wr = (wave >> 1) * 64, wc = (wave & 1) * 64;
  const int g = lane >> 4, li = lane & 15;

  const bf16* agp = X + (size_t)(m0 + (tid >> 2)) * 256 + (tid & 3) * 8;
  const bf16* bgp = W + (size_t)(n0 + (tid >> 2)) * 256 + (tid & 3) * 8;
  const int lofs = wave * 512;                     // elems; byte = wave*1024

#define QKV_STAGE(b, kt)                                                       \
  do {                                                                         \
    GLL16(agp + (kt) * 32,             &As[b][lofs]);                          \
    GLL16(agp + (kt) * 32 + 64 * 256,  &As[b][lofs + 2048]);                   \
    GLL16(bgp + (kt) * 32,             &Bs[b][lofs]);                          \
    GLL16(bgp + (kt) * 32 + 64 * 256,  &Bs[b][lofs + 2048]);                   \
  } while (0)

  const f32x4 fzero = {0.f, 0.f, 0.f, 0.f};
  f32x4 acc[4][4];
#pragma unroll
  for (int i = 0; i < 4; ++i)
#pragma unroll
    for (int j = 0; j < 4; ++j) acc[i][j] = fzero;

  QKV_STAGE(0, 0);
  __syncthreads();

#pragma unroll 1
  for (int kt = 0; kt < 8; ++kt) {
    const int cur = kt & 1;
    if (kt < 7) QKV_STAGE(cur ^ 1, kt + 1);
    bf16x8 af[4], bfr[4];
#pragma unroll
    for (int t = 0; t < 4; ++t) {
      af[t]  = *(const bf16x8*)&As[cur][(wr + t * 16 + li) * 32 + g * 8];
      bfr[t] = *(const bf16x8*)&Bs[cur][(wc + t * 16 + li) * 32 + g * 8];
    }
#pragma unroll
    for (int i = 0; i < 4; ++i)
#pragma unroll
      for (int j = 0; j < 4; ++j)
        acc[i][j] = MFMA_BF16(af[i], bfr[j], acc[i][j]);
    __syncthreads();
  }
#undef QKV_STAGE

  // epilogue: row = m0+wr+i*16+g*4+r (4-aligned), col = n0+wc+j*16+li
#pragma unroll
  for (int i = 0; i < 4; ++i) {
    const int row = m0 + wr + i * 16 + g * 4;
#pragma unroll
    for (int j = 0; j < 4; ++j) {
      const int col = n0 + wc + j * 16 + li;
      const float bv = bias[col];
      const int which = col >> 8;                 // 0=q 1=k 2=v
      if (which == 2) {
        const int hh = (col >> 5) & 7, d = col & 31;
        bf16x4 pv;
#pragma unroll
        for (int r = 0; r < 4; ++r) pv[r] = (bf16)(acc[i][j][r] + bv);
        // d-interleaved: row index (d&15)*2 + (d>>4) within the 128-elem blk
        const int drow = ((d & 15) << 1) | (d >> 4);
        *(bf16x4*)(Vg + (((size_t)hh) << 22) + (size_t)(row >> 2) * 128 + drow * 4) = pv;
      } else {
        bf16* dst = which == 0 ? Qb : Kb;
        const float sc2 = which == 0 ? QSCALE : 1.0f;   // fold scale*log2e into Q
        const size_t base = (size_t)((col >> 5) & 7) * (131072u * 32u) + (size_t)(col & 31);
#pragma unroll
        for (int r = 0; r < 4; ++r)
          dst[base + (size_t)(row + r) * 32u] = (bf16)((acc[i][j][r] + bv) * sc2);
      }
    }
  }
}

// ---------------------------------------------------------------------------
// Kernel 2: window attention. Block = (window, head), 4 waves.
// Fused QK->exp->PV, raw v_exp_f32, distance-1 packed-V prefetch, bf16x8
// bias, d-interleaved 16B V loads. (round-20 best: ~125 us)
// ---------------------------------------------------------------------------
__global__ __launch_bounds__(256)
void win_attn(const bf16* __restrict__ Qb, const bf16* __restrict__ Kb,
              const bf16* __restrict__ Vg, const bf16* __restrict__ biasB,
              bf16* __restrict__ Ob)
{
  constexpr int LDK = 40;
  __shared__ bf16 Ks[256 * LDK];     // sigma-row order, 20480 B

  const int tid = threadIdx.x;
  const int lane = tid & 63, qt = tid >> 6;
  const int li = lane & 15, g = lane >> 4;
  const int bid = blockIdx.x;
  const int h = bid & 7, w = bid >> 3;       // head fastest -> head-per-XCD
  const int b = w >> 8, wi = (w >> 4) & 15, wj = w & 15;
  const int btok = b << 14;

  // ---- Q fragment (B-operand), coalesced global ----
  const int q = qt * 16 + li;
  const int tokq = btok + (wi * 8 + (q >> 3)) * 128 + (wj * 8 + (q & 7));
  const bf16x8 qf = *(const bf16x8*)(Qb + ((((size_t)h) << 17) + tokq) * 32 + g * 8);

  // ---- stage K: 4 lanes per halo token, sigma-permuted LDS row write ----
  {
    const size_t hb = ((size_t)h) << 17;
#pragma unroll
    for (int it = 0; it < 4; ++it) {
      const int u = it * 256 + tid;
      const int m = u >> 2, c = u & 3;
      const int hi = m >> 4, hj = m & 15;
      const int gi = wi * 8 - 4 + hi, gj = wj * 8 - 4 + hj;
      const bool ok = ((unsigned)gi < 128u) && ((unsigned)gj < 128u);
      uint4 kv{};
      if (ok) kv = *(const uint4*)(Kb + (hb + (size_t)(btok + gi * 128 + gj)) * 32 + c * 8);
      const int si = ((hi & 1) << 3) | ((hj >> 3) << 2) | (hj & 3);
      const int kt = ((hi >> 1) << 1) | ((hj >> 2) & 1);
      *(uint4*)&Ks[(kt * 16 + si) * LDK + c * 8] = kv;
    }
  }
  __syncthreads();

  // ---- fused QK -> exp -> PV over 8 sigma-tile pairs ----
  // bias: biasB[h][qt][ks][g][li][8], one bf16x8 per iteration
  const bf16* bB = biasB + (size_t)(h * 4 + qt) * 4096 + (g * 16 + li) * 8;
  const f32x4 z4 = {0.f, 0.f, 0.f, 0.f};
  f32x4 o0 = z4, o1 = z4, o2 = z4;
  const bf16 one1 = (bf16)1.0f;
  const bf16x8 vones = {one1, one1, one1, one1, one1, one1, one1, one1};

  const int g1 = g & 1, g2 = g >> 1;
  const int gj0 = wj * 8 - 4 + 8 * g1;                  // 4-aligned col start
  const bool c0ok = (unsigned)gj0 < 128u;
  const bool c1ok = (unsigned)(gj0 + 4) < 128u;
  const int gi0 = wi * 8 - 4 + g2;
  // base: Vg[h][btok>>2 ...][li*8] (d-interleaved layout)
  const bf16* vb = Vg + (((size_t)h) << 22) + (size_t)(btok >> 2) * 128 + li * 8;
  const int q4a = gj0 >> 2;                             // may be negative; guarded

  // preload packed V fragments for ks = 0 (L = tokens 0-3, M = tokens 4-7;
  // each holds [d=li (4 tok), d=li+16 (4 tok)])
  bf16x8 L{}, M{};
  {
    const bool rok = (unsigned)gi0 < 128u;
    if (rok & c0ok) L = *(const bf16x8*)(vb + (size_t)(gi0 * 32 + q4a) * 128);
    if (rok & c1ok) M = *(const bf16x8*)(vb + (size_t)(gi0 * 32 + q4a + 1) * 128);
  }

#pragma unroll
  for (int ks = 0; ks < 8; ++ks) {
    // bias for tiles 2ks, 2ks+1 (bf16 -> f32 C-init)
    const bf16x8 bb = *(const bf16x8*)(bB + ks * 512);
    f32x4 cA, cB;
#pragma unroll
    for (int r = 0; r < 4; ++r) { cA[r] = (float)bb[r]; cB[r] = (float)bb[4 + r]; }

    // QK^T for sigma tiles 2ks, 2ks+1 (bias via accumulator init)
    const bf16x8 kf0 = *(const bf16x8*)&Ks[((2 * ks) * 16 + li) * LDK + g * 8];
    const bf16x8 kf1 = *(const bf16x8*)&Ks[((2 * ks + 1) * 16 + li) * LDK + g * 8];
    const f32x4 s0 = MFMA_BF16(kf0, qf, cA);
    const f32x4 s1 = MFMA_BF16(kf1, qf, cB);

    // distance-1 prefetch: packed V for iteration ks+1
    bf16x8 nL{}, nM{};
    if (ks < 7) {
      const int gi = gi0 + 2 * (ks + 1);
      const bool rok = (unsigned)gi < 128u;
      if (rok & c0ok) nL = *(const bf16x8*)(vb + (size_t)(gi * 32 + q4a) * 128);
      if (rok & c1ok) nM = *(const bf16x8*)(vb + (size_t)(gi * 32 + q4a + 1) * 128);
    }

    // raw exp2 -> bf16 P fragment (in-lane via sigma order)
    bf16x8 pb;
#pragma unroll
    for (int u = 0; u < 4; ++u) {
      pb[u]     = (bf16)__builtin_amdgcn_exp2f(s0[u]);
      pb[u + 4] = (bf16)__builtin_amdgcn_exp2f(s1[u]);
    }
    // unpack: vf0 = [L.d=li, M.d=li], vf1 = [L.d=li+16, M.d=li+16]
    const bf16x8 vf0 = __builtin_shufflevector(L, M, 0, 1, 2, 3, 8, 9, 10, 11);
    const bf16x8 vf1 = __builtin_shufflevector(L, M, 4, 5, 6, 7, 12, 13, 14, 15);
    o0 = MFMA_BF16(vf0, pb, o0);
    o1 = MFMA_BF16(vf1, pb, o1);
    o2 = MFMA_BF16(vones, pb, o2);

    L = nL; M = nM;
  }
  const float inv = __builtin_amdgcn_rcpf(o2[0]);

  // ---- epilogue: O[tokq][h*32 + dt*16 + 4g + r] = O^T/sum ----
  bf16* op = Ob + (size_t)tokq * 256 + h * 32 + 4 * g;
  bf16x4 w0, w1;
#pragma unroll
  for (int r = 0; r < 4; ++r) {
    w0[r] = (bf16)(o0[r] * inv);
    w1[r] = (bf16)(o1[r] * inv);
  }
  *(bf16x4*)(op) = w0;
  *(bf16x4*)(op + 16) = w1;
}

// ---------------------------------------------------------------------------
// Kernel 3: out = attn_out @ proj_w.T + proj_b   (fp32 output to d_out)
// 2-phase: A (bf16) via global_load_lds into linear dbuf LDS; B (fp32 W)
// reg-staged+converted into padded dbuf LDS. One barrier per K-step.
// ---------------------------------------------------------------------------
__global__ __launch_bounds__(256, 2)
void proj_gemm(const bf16* __restrict__ A, const float* __restrict__ W,
               const float* __restrict__ bias, float* __restrict__ Out)
{
  __shared__ bf16 As[2][128 * 32];   // linear, gload_lds dest
  __shared__ bf16 Bs[2][128 * 40];   // padded, reg-staged

  const int tid = threadIdx.x;
  const int lane = tid & 63, wave = tid >> 6;
  const int bid = blockIdx.x;
  const int wid = (bid & 7) * 256 + (bid >> 3);   // XCD-contiguous work id
  const int bn = wid & 1, bm = wid >> 1;
  const int m0 = bm * 128, n0 = bn * 128;
  const int sr = tid >> 1, sc = (tid & 1) * 16;
  const int wr = (wave >> 1) * 64, wc = (wave & 1) * 64;
  const int g = lane >> 4, li = lane & 15;

  const bf16* agp = A + (size_t)(m0 + (tid >> 2)) * 256 + (tid & 3) * 8;
  const float* Bp = W + (size_t)(n0 + sr) * 256 + sc;
  const int lofs = wave * 512;

  const f32x4 fzero = {0.f, 0.f, 0.f, 0.f};
  f32x4 acc[4][4];
#pragma unroll
  for (int i = 0; i < 4; ++i)
#pragma unroll
    for (int j = 0; j < 4; ++j) acc[i][j] = fzero;

  float bR[16];
  load16f(Bp, bR);
  GLL16(agp,            &As[0][lofs]);
  GLL16(agp + 64 * 256, &As[0][lofs + 2048]);
  store16_bf16(&Bs[0][sr * 40 + sc], bR);
  load16f(Bp + 32, bR);
  __syncthreads();

#pragma unroll 1
  for (int kt = 0; kt < 8; ++kt) {
    const int cur = kt & 1;
    if (kt < 7) {
      GLL16(agp + (kt + 1) * 32,            &As[cur ^ 1][lofs]);
      GLL16(agp + (kt + 1) * 32 + 64 * 256, &As[cur ^ 1][lofs + 2048]);
      store16_bf16(&Bs[cur ^ 1][sr * 40 + sc], bR);
      if (kt < 6) load16f(Bp + (kt + 2) * 32, bR);
    }
    bf16x8 af[4], bfr[4];
#pragma unroll
    for (int t = 0; t < 4; ++t) {
      af[t]  = *(const bf16x8*)&As[cur][(wr + t * 16 + li) * 32 + g * 8];
      bfr[t] = *(const bf16x8*)&Bs[cur][(wc + t * 16 + li) * 40 + g * 8];
    }
#pragma unroll
    for (int i = 0; i < 4; ++i)
#pragma unroll
      for (int j = 0; j < 4; ++j)
        acc[i][j] = MFMA_BF16(af[i], bfr[j], acc[i][j]);
    __syncthreads();
  }

#pragma unroll
  for (int i = 0; i < 4; ++i) {
    const int row = m0 + wr + i * 16 + g * 4;
#pragma unroll
    for (int j = 0; j < 4; ++j) {
      const int col = n0 + wc + j * 16 + li;
      const float bv = bias[col];
#pragma unroll
      for (int r = 0; r < 4; ++r)
        Out[(size_t)(row + r) * 256 + col] = acc[i][j][r] + bv;
    }
  }
}

// ---------------------------------------------------------------------------
extern "C" void kernel_launch(void* const* d_in, const int* in_sizes, int n_in,
                              void* d_out, int out_size, void* d_ws, size_t ws_size,
                              hipStream_t stream)
{
  const float* x       = (const float*)d_in[0];
  // d_in[1] = mask: unused by the reference
  const float* qkv_w   = (const float*)d_in[2];
  const float* qkv_b   = (const float*)d_in[3];
  const float* proj_w  = (const float*)d_in[4];
  const float* proj_b  = (const float*)d_in[5];
  const float* rel_tab = (const float*)d_in[6];
  float* out = (float*)d_out;

  char* ws = (char*)d_ws;
  bf16* Qb = (bf16*)(ws);                            // [8h][131072][32]       64 MiB
  bf16* Kb = (bf16*)(ws + (size_t)67108864);         // [8h][131072][32]       64 MiB
  bf16* Vg = (bf16*)(ws + (size_t)134217728);        // [8h][32768][64][4]     64 MiB
  bf16* Ao = (bf16*)(ws + (size_t)201326592);        // [131072][256]          64 MiB
  // Xb aliases the Ao region: live only between cvt_bf16 and qkv_gemm.
  bf16* Xb = Ao;
  // d_out scratch (proj_gemm overwrites all of d_out at the end):
  bf16*  biasB = (bf16*)d_out;                           // 256 KB
  bf16*  Wqb   = (bf16*)((char*)d_out + 1048576);        // 384 KB

  cvt_bf16<<<dim3(16480), dim3(256), 0, stream>>>(x, qkv_w, Xb, Wqb);
  bias_pre<<<dim3(64), dim3(256), 0, stream>>>(rel_tab, biasB);
  qkv_gemm<<<dim3(6144), dim3(256), 0, stream>>>(Xb, Wqb, qkv_b, Qb, Kb, Vg);
  win_attn<<<dim3(16384), dim3(256), 0, stream>>>(Qb, Kb, Vg, biasB, Ao);
  proj_gemm<<<dim3(2048), dim3(256), 0, stream>>>(Ao, proj_w, proj_b, out);
}